// Round 3
// baseline (1094.727 us; speedup 1.0000x reference)
//
#include <hip/hip_runtime.h>

// VQ-VAE EMA quantizer. B=32, D=64, T=2048, K=1024, N=B*T=65536.
// Outputs (f32, concat): quantized[32*64*2048], loss[1], codes[32*2048],
//   new_embedding[1024*64], new_cs[1024], new_w[1024*64]  -> 4391937 total.
//
// R3 design: wave-uniform code slabs -> embedding rows load via the SCALAR
// path (s_load -> SGPR, v_fma v,s,v), so the 8.6 GFLOP distance phase is pure
// FMA issue instead of L1-thrashing vector loads (R2: VALUBusy 20.6%).

constexpr int Bn = 32, Dn = 64, Tn = 2048, Kn = 1024;
constexpr float DECAY = 0.99f, ONE_MINUS_DECAY = 0.01f, EPSV = 1e-5f, COMMIT = 0.25f;

// ---------------- esq: per-code squared norm ----------------
__global__ __launch_bounds__(256) void vq_esq_kernel(const float* __restrict__ emb,
                                                     float* __restrict__ esq) {
  int k = blockIdx.x * 256 + threadIdx.x;
  if (k >= Kn) return;
  const float4* e4 = reinterpret_cast<const float4*>(emb + (size_t)k * Dn);
  float a0 = 0.f, a1 = 0.f, a2 = 0.f, a3 = 0.f;
#pragma unroll
  for (int q = 0; q < 16; ++q) {
    float4 v = e4[q];
    a0 = fmaf(v.x, v.x, a0);
    a1 = fmaf(v.y, v.y, a1);
    a2 = fmaf(v.z, v.z, a2);
    a3 = fmaf(v.w, v.w, a3);
  }
  esq[k] = (a0 + a1) + (a2 + a3);
}

// ---------------- main ----------------
// Block: 256 threads = 4 waves; 64 tokens/block (consecutive t, same b).
// Thread (l = tid&63, w = tid>>6): token l, codes [w*256, w*256+256).
// Code addresses are wave-uniform -> scalar loads.
__global__ __launch_bounds__(256, 4) void vq_main_kernel(
    const float* __restrict__ z, const float* __restrict__ emb,
    const float* __restrict__ esq, float* __restrict__ out_quant,
    float* __restrict__ out_codes, float* __restrict__ counts,
    float* __restrict__ dw, float* __restrict__ loss_acc) {
  __shared__ float red_d[4][64];
  __shared__ int   red_i[4][64];
  __shared__ int   idxs[64];
  __shared__ float lred[4];

  const int tid = threadIdx.x;
  const int l = tid & 63;                                   // lane / token slot
  const int w = __builtin_amdgcn_readfirstlane(tid >> 6);   // wave id (uniform)

  const int tok = blockIdx.x * 64 + l;
  const int b = tok >> 11;            // 2048 tokens per batch elem
  const int t = tok & 2047;
  const float* zb = z + (size_t)b * (Dn * Tn) + t;

  // ---- token's z row into registers (coalesced: lanes = consecutive t) ----
  float zr[64];
#pragma unroll
  for (int d = 0; d < 64; ++d) zr[d] = zb[(size_t)d * Tn];
  float q0 = 0.f, q1 = 0.f, q2 = 0.f, q3 = 0.f;
#pragma unroll
  for (int d = 0; d < 64; d += 4) {
    q0 = fmaf(zr[d + 0], zr[d + 0], q0);
    q1 = fmaf(zr[d + 1], zr[d + 1], q1);
    q2 = fmaf(zr[d + 2], zr[d + 2], q2);
    q3 = fmaf(zr[d + 3], zr[d + 3], q3);
  }
  const float zsq = (q0 + q1) + (q2 + q3);

  // ---- scan this wave's 256 codes; addresses wave-uniform ----
  float mind = INFINITY;
  int midx = 0;
  const int c0 = w * 256;
  for (int c = c0; c < c0 + 256; ++c) {
    const float4* e4 = reinterpret_cast<const float4*>(emb + (size_t)c * Dn);
    float a0 = 0.f, a1 = 0.f, a2 = 0.f, a3 = 0.f;
#pragma unroll
    for (int q = 0; q < 16; ++q) {
      float4 ev = e4[q];
      a0 = fmaf(zr[q * 4 + 0], ev.x, a0);
      a1 = fmaf(zr[q * 4 + 1], ev.y, a1);
      a2 = fmaf(zr[q * 4 + 2], ev.z, a2);
      a3 = fmaf(zr[q * 4 + 3], ev.w, a3);
    }
    float dot = (a0 + a1) + (a2 + a3);
    float dist = fmaf(-2.f, dot, zsq + esq[c]);
    if (dist < mind) { mind = dist; midx = c; }   // ascending c => first min kept
  }
  red_d[w][l] = mind;
  red_i[w][l] = midx;
  __syncthreads();

  // ---- cross-wave argmin (first-index tie-break), codes, counts ----
  if (tid < 64) {
    float md = red_d[0][tid];
    int mi = red_i[0][tid];
#pragma unroll
    for (int s = 1; s < 4; ++s) {
      float dv = red_d[s][tid];
      int iv = red_i[s][tid];
      if (dv < md || (dv == md && iv < mi)) { md = dv; mi = iv; }
    }
    idxs[tid] = mi;
    out_codes[(size_t)b * Tn + (blockIdx.x & 31) * 64 + tid] = (float)mi;
    atomicAdd(&counts[mi], 1.0f);
  }
  __syncthreads();

  // ---- epilogue: wave w handles dims [16w,16w+16) of every token ----
  const int myidx = idxs[l];
  const float* erow = emb + (size_t)myidx * Dn;
  float* qout = out_quant + (size_t)b * (Dn * Tn) + t;
  float lpart = 0.f;
#pragma unroll
  for (int j = 0; j < 16; ++j) {
    int d = w * 16 + j;
    float e = erow[d];
    float zv = zr[d];
    qout[(size_t)d * Tn] = e;                       // coalesced along t
    atomicAdd(&dw[(size_t)myidx * Dn + d], zv);
    float diff = e - zv;
    lpart = fmaf(diff, diff, lpart);                // reference's direct loss
  }
#pragma unroll
  for (int off = 32; off > 0; off >>= 1) lpart += __shfl_down(lpart, off, 64);
  if (l == 0) lred[w] = lpart;
  __syncthreads();
  if (tid == 0) atomicAdd(loss_acc, (lred[0] + lred[1]) + (lred[2] + lred[3]));
}

// ---------------- finalize part 1: new_cs, n, loss ----------------
__global__ __launch_bounds__(1024) void vq_final1_kernel(
    const float* __restrict__ ema_cs, const float* __restrict__ counts,
    const float* __restrict__ loss_acc, float* __restrict__ out_newcs,
    float* __restrict__ out_loss, float* __restrict__ n_out) {
  __shared__ float sred[1024];
  const int tid = threadIdx.x;
  float cs = fmaf(ONE_MINUS_DECAY, counts[tid], DECAY * ema_cs[tid]);
  out_newcs[tid] = cs;
  sred[tid] = cs;
  __syncthreads();
  for (int s = 512; s > 0; s >>= 1) {
    if (tid < s) sred[tid] += sred[tid + s];
    __syncthreads();
  }
  if (tid == 0) {
    n_out[0] = sred[0];
    out_loss[0] = COMMIT * loss_acc[0] / (float)(Bn * Tn * Dn);
  }
}

// ---------------- finalize part 2: new_w, new_embedding ----------------
__global__ __launch_bounds__(256) void vq_final2_kernel(
    const float* __restrict__ ema_w, const float* __restrict__ dw,
    const float* __restrict__ newcs, const float* __restrict__ n_in,
    float* __restrict__ out_neww, float* __restrict__ out_newemb) {
  const int i = blockIdx.x * 256 + threadIdx.x;   // 0..65535
  const int k = i >> 6;
  const float n = n_in[0];
  const float cl = (newcs[k] + EPSV) / (n + (float)Kn * EPSV) * n;
  const float w = fmaf(ONE_MINUS_DECAY, dw[i], DECAY * ema_w[i]);
  out_neww[i] = w;
  out_newemb[i] = w / cl;
}

extern "C" void kernel_launch(void* const* d_in, const int* in_sizes, int n_in,
                              void* d_out, int out_size, void* d_ws, size_t ws_size,
                              hipStream_t stream) {
  const float* z      = (const float*)d_in[0];
  const float* emb    = (const float*)d_in[1];
  const float* ema_cs = (const float*)d_in[2];
  const float* ema_w  = (const float*)d_in[3];

  float* out = (float*)d_out;
  float* o_quant  = out;                       // 4194304
  float* o_loss   = out + 4194304;             // 1
  float* o_codes  = out + 4194305;             // 65536
  float* o_newemb = out + 4259841;             // 65536
  float* o_newcs  = out + 4325377;             // 1024
  float* o_neww   = out + 4326401;             // 65536

  float* ws       = (float*)d_ws;
  float* counts   = ws;                        // 1024
  float* dw       = ws + 1024;                 // 65536
  float* loss_acc = ws + 66560;                // 1
  float* nval     = ws + 66561;                // 1
  float* esq      = ws + 66562;                // 1024

  hipMemsetAsync(ws, 0, (size_t)66561 * sizeof(float), stream);

  vq_esq_kernel<<<4, 256, 0, stream>>>(emb, esq);
  vq_main_kernel<<<1024, 256, 0, stream>>>(z, emb, esq, o_quant, o_codes,
                                           counts, dw, loss_acc);
  vq_final1_kernel<<<1, 1024, 0, stream>>>(ema_cs, counts, loss_acc,
                                           o_newcs, o_loss, nval);
  vq_final2_kernel<<<256, 256, 0, stream>>>(ema_w, dw, o_newcs, nval,
                                            o_neww, o_newemb);
}

// Round 4
// 996.524 us; speedup vs baseline: 1.0985x; 1.0985x over previous
//
#include <hip/hip_runtime.h>

// VQ-VAE EMA quantizer. B=32, D=64, T=2048, K=1024, N=B*T=65536.
// Outputs (f32, concat): quantized[4194304], loss[1], codes[65536],
//   new_embedding[65536], new_cs[1024], new_w[65536].
//
// R4: register-tiled LDS GEMM for the distance phase.
//   Block = 512 thr (8 waves): 128 tokens x 128-code chunks (x8 chunks).
//   Thread = 4 tokens x 8 codes outer product: 32 FMA per 3 ds_read_b128.
//   R2 lesson: per-thread global streaming of emb = latency-bound (VALU 21%).
//   R3 lesson: scalar-pipe (s_load) streaming is worse (VALU 7%). LDS it is.

constexpr int Bn = 32, Dn = 64, Tn = 2048, Kn = 1024;
constexpr float DECAY = 0.99f, OMD = 0.01f, EPSV = 1e-5f, COMMIT = 0.25f;

// ---------------- esq: per-code squared norm ----------------
__global__ __launch_bounds__(256) void vq_esq_kernel(const float* __restrict__ emb,
                                                     float* __restrict__ esq) {
  int k = blockIdx.x * 256 + threadIdx.x;
  if (k >= Kn) return;
  const float4* e4 = reinterpret_cast<const float4*>(emb + (size_t)k * Dn);
  float a0 = 0.f, a1 = 0.f, a2 = 0.f, a3 = 0.f;
#pragma unroll
  for (int q = 0; q < 16; ++q) {
    float4 v = e4[q];
    a0 = fmaf(v.x, v.x, a0);
    a1 = fmaf(v.y, v.y, a1);
    a2 = fmaf(v.z, v.z, a2);
    a3 = fmaf(v.w, v.w, a3);
  }
  esq[k] = (a0 + a1) + (a2 + a3);
}

// ---------------- main ----------------
__global__ __launch_bounds__(512, 4) void vq_main_kernel(
    const float* __restrict__ z, const float* __restrict__ emb,
    const float* __restrict__ esq_g, float* __restrict__ out_quant,
    float* __restrict__ out_codes, float* __restrict__ counts,
    float* __restrict__ dw, float* __restrict__ loss_acc) {
  __shared__ float As[64][132];     // A[k][token], +4 pad: conflict-free reads
  __shared__ float Bs[64 * 128];    // B[k][code]; later reused for argmin merge
  __shared__ float zsq_s[128];
  __shared__ float esq_s[128];
  __shared__ float lred[8];

  const int tid = threadIdx.x;
  const int blk = blockIdx.x;          // 512 blocks
  const int b  = blk >> 4;             // 16 blocks per batch element
  const int t0 = (blk & 15) * 128;
  const float* zb = z + (size_t)b * (Dn * Tn) + t0;

  // ---- stage A (once): thread d=tid>>3 stages 16 floats of row d ----
  {
    const int d = tid >> 3, seg = tid & 7;
    const float4* src = reinterpret_cast<const float4*>(zb + (size_t)d * Tn + 16 * seg);
#pragma unroll
    for (int j = 0; j < 4; ++j) {
      *reinterpret_cast<float4*>(&As[d][16 * seg + 4 * j]) = src[j];
    }
  }
  __syncthreads();

  // ---- per-token zsq (threads 0..127), visible after first chunk barrier ----
  if (tid < 128) {
    float a0 = 0.f, a1 = 0.f, a2 = 0.f, a3 = 0.f;
#pragma unroll
    for (int k = 0; k < 64; k += 4) {
      a0 = fmaf(As[k + 0][tid], As[k + 0][tid], a0);
      a1 = fmaf(As[k + 1][tid], As[k + 1][tid], a1);
      a2 = fmaf(As[k + 2][tid], As[k + 2][tid], a2);
      a3 = fmaf(As[k + 3][tid], As[k + 3][tid], a3);
    }
    zsq_s[tid] = (a0 + a1) + (a2 + a3);
  }

  const int n_t = tid & 15;     // 16 code-threads: codes {4n_t+j, 64+4n_t+j}
  const int m_t = tid >> 4;     // 32 token-threads: tokens 4m_t..4m_t+3

  float mind[4] = {INFINITY, INFINITY, INFINITY, INFINITY};
  int   mini[4] = {0, 0, 0, 0};

  for (int c8 = 0; c8 < 8; ++c8) {
    const int c0 = c8 * 128;
    // ---- stage B chunk (transpose to [k][code]) + esq slice ----
    {
      const int cl = tid >> 2, q = tid & 3;   // code cl, k-quad q
      const float4* src = reinterpret_cast<const float4*>(emb + (size_t)(c0 + cl) * Dn + 16 * q);
#pragma unroll
      for (int u = 0; u < 4; ++u) {
        float4 v = src[u];
        const int kb = 16 * q + 4 * u;
        Bs[(kb + 0) * 128 + cl] = v.x;
        Bs[(kb + 1) * 128 + cl] = v.y;
        Bs[(kb + 2) * 128 + cl] = v.z;
        Bs[(kb + 3) * 128 + cl] = v.w;
      }
      if (tid < 128) esq_s[tid] = esq_g[c0 + tid];
    }
    __syncthreads();

    float acc[4][8];
#pragma unroll
    for (int m = 0; m < 4; ++m)
#pragma unroll
      for (int j = 0; j < 8; ++j) acc[m][j] = 0.f;

#pragma unroll 8
    for (int k = 0; k < 64; ++k) {
      float4 av = *reinterpret_cast<const float4*>(&As[k][4 * m_t]);
      float4 b0 = *reinterpret_cast<const float4*>(&Bs[k * 128 + 4 * n_t]);
      float4 b1 = *reinterpret_cast<const float4*>(&Bs[k * 128 + 64 + 4 * n_t]);
      const float a[4]  = {av.x, av.y, av.z, av.w};
      const float bb[8] = {b0.x, b0.y, b0.z, b0.w, b1.x, b1.y, b1.z, b1.w};
#pragma unroll
      for (int m = 0; m < 4; ++m)
#pragma unroll
        for (int j = 0; j < 8; ++j)
          acc[m][j] = fmaf(a[m], bb[j], acc[m][j]);
    }

    // ---- distances + running (min, idx); ascending code order kept ----
#pragma unroll
    for (int m = 0; m < 4; ++m) {
      const float zq = zsq_s[4 * m_t + m];
#pragma unroll
      for (int j = 0; j < 8; ++j) {
        const int cc = (j < 4) ? (4 * n_t + j) : (64 + 4 * n_t + (j - 4));
        const float dist = fmaf(-2.f, acc[m][j], zq + esq_s[cc]);
        if (dist < mind[m]) { mind[m] = dist; mini[m] = c0 + cc; }
      }
    }
    __syncthreads();   // before next chunk overwrites Bs
  }

  // ---- cross-thread argmin merge (reuse Bs; stride 17 = conflict-free) ----
  float* red_d = Bs;                         // [128][17]
  int*   red_i = (int*)(Bs + 2176);
  int*   idxs  = (int*)(Bs + 4352);
#pragma unroll
  for (int m = 0; m < 4; ++m) {
    red_d[(4 * m_t + m) * 17 + n_t] = mind[m];
    red_i[(4 * m_t + m) * 17 + n_t] = mini[m];
  }
  __syncthreads();
  if (tid < 128) {
    float md = red_d[tid * 17];
    int mi = red_i[tid * 17];
#pragma unroll
    for (int s = 1; s < 16; ++s) {
      float dv = red_d[tid * 17 + s];
      int iv = red_i[tid * 17 + s];
      if (dv < md || (dv == md && iv < mi)) { md = dv; mi = iv; }
    }
    idxs[tid] = mi;
    out_codes[(size_t)b * Tn + t0 + tid] = (float)mi;
    atomicAdd(&counts[mi], 1.0f);
  }
  __syncthreads();

  // ---- epilogue: quant write, dw atomics, direct loss ----
  const int l = tid & 127, g = tid >> 7;     // token l, dim group g (16 dims)
  const int myidx = idxs[l];
  const float* erow = emb + (size_t)myidx * Dn;
  float* qout = out_quant + (size_t)b * (Dn * Tn) + t0 + l;
  float lpart = 0.f;
#pragma unroll
  for (int j = 0; j < 16; ++j) {
    const int d = 16 * g + j;
    const float e = erow[d];
    const float zv = As[d][l];
    qout[(size_t)d * Tn] = e;                      // coalesced along t
    atomicAdd(&dw[(size_t)myidx * Dn + d], zv);
    const float diff = e - zv;
    lpart = fmaf(diff, diff, lpart);               // reference's direct loss
  }
#pragma unroll
  for (int off = 32; off > 0; off >>= 1) lpart += __shfl_down(lpart, off, 64);
  if ((tid & 63) == 0) lred[tid >> 6] = lpart;
  __syncthreads();
  if (tid == 0) {
    float s = 0.f;
#pragma unroll
    for (int w8 = 0; w8 < 8; ++w8) s += lred[w8];
    atomicAdd(loss_acc, s);
  }
}

// ---------------- finalize part 1: new_cs, n, loss ----------------
__global__ __launch_bounds__(1024) void vq_final1_kernel(
    const float* __restrict__ ema_cs, const float* __restrict__ counts,
    const float* __restrict__ loss_acc, float* __restrict__ out_newcs,
    float* __restrict__ out_loss, float* __restrict__ n_out) {
  __shared__ float sred[1024];
  const int tid = threadIdx.x;
  float cs = fmaf(OMD, counts[tid], DECAY * ema_cs[tid]);
  out_newcs[tid] = cs;
  sred[tid] = cs;
  __syncthreads();
  for (int s = 512; s > 0; s >>= 1) {
    if (tid < s) sred[tid] += sred[tid + s];
    __syncthreads();
  }
  if (tid == 0) {
    n_out[0] = sred[0];
    out_loss[0] = COMMIT * loss_acc[0] / (float)(Bn * Tn * Dn);
  }
}

// ---------------- finalize part 2: new_w, new_embedding ----------------
__global__ __launch_bounds__(256) void vq_final2_kernel(
    const float* __restrict__ ema_w, const float* __restrict__ dw,
    const float* __restrict__ newcs, const float* __restrict__ n_in,
    float* __restrict__ out_neww, float* __restrict__ out_newemb) {
  const int i = blockIdx.x * 256 + threadIdx.x;   // 0..65535
  const int k = i >> 6;
  const float n = n_in[0];
  const float cl = (newcs[k] + EPSV) / (n + (float)Kn * EPSV) * n;
  const float w = fmaf(OMD, dw[i], DECAY * ema_w[i]);
  out_neww[i] = w;
  out_newemb[i] = w / cl;
}

extern "C" void kernel_launch(void* const* d_in, const int* in_sizes, int n_in,
                              void* d_out, int out_size, void* d_ws, size_t ws_size,
                              hipStream_t stream) {
  const float* z      = (const float*)d_in[0];
  const float* emb    = (const float*)d_in[1];
  const float* ema_cs = (const float*)d_in[2];
  const float* ema_w  = (const float*)d_in[3];

  float* out = (float*)d_out;
  float* o_quant  = out;                       // 4194304
  float* o_loss   = out + 4194304;             // 1
  float* o_codes  = out + 4194305;             // 65536
  float* o_newemb = out + 4259841;             // 65536
  float* o_newcs  = out + 4325377;             // 1024
  float* o_neww   = out + 4326401;             // 65536

  float* ws       = (float*)d_ws;
  float* counts   = ws;                        // 1024
  float* dw       = ws + 1024;                 // 65536
  float* loss_acc = ws + 66560;                // 1
  float* nval     = ws + 66561;                // 1
  float* esq      = ws + 66562;                // 1024

  hipMemsetAsync(ws, 0, (size_t)66561 * sizeof(float), stream);

  vq_esq_kernel<<<4, 256, 0, stream>>>(emb, esq);
  vq_main_kernel<<<512, 512, 0, stream>>>(z, emb, esq, o_quant, o_codes,
                                          counts, dw, loss_acc);
  vq_final1_kernel<<<1, 1024, 0, stream>>>(ema_cs, counts, loss_acc,
                                           o_newcs, o_loss, nval);
  vq_final2_kernel<<<256, 256, 0, stream>>>(ema_w, dw, o_newcs, nval,
                                            o_neww, o_newemb);
}

// Round 12
// 355.990 us; speedup vs baseline: 3.0752x; 2.7993x over previous
//
#include <hip/hip_runtime.h>

// VQ-VAE EMA quantizer. B=32, D=64, T=2048, K=1024, N=B*T=65536.
// Outputs (f32, concat): quantized[4194304], loss[1], codes[65536],
//   new_embedding[65536], new_cs[1024], new_w[65536].
//
// R5: kill the 4.2M global atomics (R2/R3/R4 all ~800-1000us regardless of
// GEMM structure; WRITE_SIZE ~153MB = atomic RMW writeback => atomics were
// the bottleneck). dw/counts now computed by a per-code gather kernel with
// wave-ballot list compaction. Main kernel keeps R4's tiled GEMM unchanged.

constexpr int Bn = 32, Dn = 64, Tn = 2048, Kn = 1024;
constexpr float DECAY = 0.99f, OMD = 0.01f, EPSV = 1e-5f, COMMIT = 0.25f;

// ---------------- kernel 1: esq (blocks 0-3) + sum(ema_cs) -> n (block 4) ----
__global__ __launch_bounds__(256) void vq_prep_kernel(const float* __restrict__ emb,
                                                      const float* __restrict__ ema_cs,
                                                      float* __restrict__ esq,
                                                      float* __restrict__ nval) {
  if (blockIdx.x < 4) {
    int k = blockIdx.x * 256 + threadIdx.x;
    const float4* e4 = reinterpret_cast<const float4*>(emb + (size_t)k * Dn);
    float a0 = 0.f, a1 = 0.f, a2 = 0.f, a3 = 0.f;
#pragma unroll
    for (int q = 0; q < 16; ++q) {
      float4 v = e4[q];
      a0 = fmaf(v.x, v.x, a0);
      a1 = fmaf(v.y, v.y, a1);
      a2 = fmaf(v.z, v.z, a2);
      a3 = fmaf(v.w, v.w, a3);
    }
    esq[k] = (a0 + a1) + (a2 + a3);
  } else {
    __shared__ float wred[4];
    const int tid = threadIdx.x;
    float s = ema_cs[tid] + ema_cs[tid + 256] + ema_cs[tid + 512] + ema_cs[tid + 768];
#pragma unroll
    for (int off = 32; off > 0; off >>= 1) s += __shfl_down(s, off, 64);
    if ((tid & 63) == 0) wred[tid >> 6] = s;
    __syncthreads();
    if (tid == 0)
      nval[0] = fmaf(DECAY, (wred[0] + wred[1]) + (wred[2] + wred[3]),
                     OMD * (float)(Bn * Tn));
  }
}

// ---------------- kernel 2: distances, argmin, codes, quant, loss ----------------
__global__ __launch_bounds__(512, 4) void vq_main_kernel(
    const float* __restrict__ z, const float* __restrict__ emb,
    const float* __restrict__ esq_g, float* __restrict__ out_quant,
    float* __restrict__ out_codes, float* __restrict__ loss_acc) {
  __shared__ float As[64][132];     // A[k][token], +4 pad
  __shared__ float Bs[64 * 128];    // B[k][code]; reused for argmin merge
  __shared__ float zsq_s[128];
  __shared__ float esq_s[128];
  __shared__ float lred[8];

  const int tid = threadIdx.x;
  const int blk = blockIdx.x;          // 512 blocks
  const int b  = blk >> 4;             // 16 blocks per batch element
  const int t0 = (blk & 15) * 128;
  const float* zb = z + (size_t)b * (Dn * Tn) + t0;

  // ---- stage A (once): thread d=tid>>3 stages 16 floats of row d ----
  {
    const int d = tid >> 3, seg = tid & 7;
    const float4* src = reinterpret_cast<const float4*>(zb + (size_t)d * Tn + 16 * seg);
#pragma unroll
    for (int j = 0; j < 4; ++j)
      *reinterpret_cast<float4*>(&As[d][16 * seg + 4 * j]) = src[j];
  }
  __syncthreads();

  if (tid < 128) {
    float a0 = 0.f, a1 = 0.f, a2 = 0.f, a3 = 0.f;
#pragma unroll
    for (int k = 0; k < 64; k += 4) {
      a0 = fmaf(As[k + 0][tid], As[k + 0][tid], a0);
      a1 = fmaf(As[k + 1][tid], As[k + 1][tid], a1);
      a2 = fmaf(As[k + 2][tid], As[k + 2][tid], a2);
      a3 = fmaf(As[k + 3][tid], As[k + 3][tid], a3);
    }
    zsq_s[tid] = (a0 + a1) + (a2 + a3);
  }

  const int n_t = tid & 15;     // codes {4n_t+j, 64+4n_t+j} per chunk
  const int m_t = tid >> 4;     // tokens 4m_t..4m_t+3

  float mind[4] = {INFINITY, INFINITY, INFINITY, INFINITY};
  int   mini[4] = {0, 0, 0, 0};

  for (int c8 = 0; c8 < 8; ++c8) {
    const int c0 = c8 * 128;
    {
      const int cl = tid >> 2, q = tid & 3;
      const float4* src = reinterpret_cast<const float4*>(emb + (size_t)(c0 + cl) * Dn + 16 * q);
#pragma unroll
      for (int u = 0; u < 4; ++u) {
        float4 v = src[u];
        const int kb = 16 * q + 4 * u;
        Bs[(kb + 0) * 128 + cl] = v.x;
        Bs[(kb + 1) * 128 + cl] = v.y;
        Bs[(kb + 2) * 128 + cl] = v.z;
        Bs[(kb + 3) * 128 + cl] = v.w;
      }
      if (tid < 128) esq_s[tid] = esq_g[c0 + tid];
    }
    __syncthreads();

    float acc[4][8];
#pragma unroll
    for (int m = 0; m < 4; ++m)
#pragma unroll
      for (int j = 0; j < 8; ++j) acc[m][j] = 0.f;

#pragma unroll 8
    for (int k = 0; k < 64; ++k) {
      float4 av = *reinterpret_cast<const float4*>(&As[k][4 * m_t]);
      float4 b0 = *reinterpret_cast<const float4*>(&Bs[k * 128 + 4 * n_t]);
      float4 b1 = *reinterpret_cast<const float4*>(&Bs[k * 128 + 64 + 4 * n_t]);
      const float a[4]  = {av.x, av.y, av.z, av.w};
      const float bb[8] = {b0.x, b0.y, b0.z, b0.w, b1.x, b1.y, b1.z, b1.w};
#pragma unroll
      for (int m = 0; m < 4; ++m)
#pragma unroll
        for (int j = 0; j < 8; ++j)
          acc[m][j] = fmaf(a[m], bb[j], acc[m][j]);
    }

#pragma unroll
    for (int m = 0; m < 4; ++m) {
      const float zq = zsq_s[4 * m_t + m];
#pragma unroll
      for (int j = 0; j < 8; ++j) {
        const int cc = (j < 4) ? (4 * n_t + j) : (64 + 4 * n_t + (j - 4));
        const float dist = fmaf(-2.f, acc[m][j], zq + esq_s[cc]);
        if (dist < mind[m]) { mind[m] = dist; mini[m] = c0 + cc; }
      }
    }
    __syncthreads();
  }

  // ---- cross-thread argmin merge (reuse Bs; stride 17) ----
  float* red_d = Bs;
  int*   red_i = (int*)(Bs + 2176);
  int*   idxs  = (int*)(Bs + 4352);
#pragma unroll
  for (int m = 0; m < 4; ++m) {
    red_d[(4 * m_t + m) * 17 + n_t] = mind[m];
    red_i[(4 * m_t + m) * 17 + n_t] = mini[m];
  }
  __syncthreads();
  if (tid < 128) {
    float md = red_d[tid * 17];
    int mi = red_i[tid * 17];
#pragma unroll
    for (int s = 1; s < 16; ++s) {
      float dv = red_d[tid * 17 + s];
      int iv = red_i[tid * 17 + s];
      if (dv < md || (dv == md && iv < mi)) { md = dv; mi = iv; }
    }
    idxs[tid] = mi;
    out_codes[(size_t)b * Tn + t0 + tid] = (float)mi;
  }
  __syncthreads();

  // ---- epilogue: quant write + direct loss (NO dw/counts atomics) ----
  const int l = tid & 127, g = tid >> 7;
  const int myidx = idxs[l];
  const float* erow = emb + (size_t)myidx * Dn;
  float* qout = out_quant + (size_t)b * (Dn * Tn) + t0 + l;
  float lpart = 0.f;
#pragma unroll
  for (int j = 0; j < 16; ++j) {
    const int d = 16 * g + j;
    const float e = erow[d];
    const float diff = e - As[d][l];
    qout[(size_t)d * Tn] = e;
    lpart = fmaf(diff, diff, lpart);
  }
#pragma unroll
  for (int off = 32; off > 0; off >>= 1) lpart += __shfl_down(lpart, off, 64);
  if ((tid & 63) == 0) lred[tid >> 6] = lpart;
  __syncthreads();
  if (tid == 0) {
    float s = 0.f;
#pragma unroll
    for (int w8 = 0; w8 < 8; ++w8) s += lred[w8];
    atomicAdd(loss_acc, s);
  }
}

// ---------------- kernel 3: per-code gather -> counts, dw, all EMA outputs ----
// Block k owns code k. Scan codes[] in 8192-token windows; wave-ballot
// compaction into an LDS token list; 4 token-groups x 64 dims drain gather.
__global__ __launch_bounds__(256) void vq_dw_kernel(
    const float* __restrict__ z, const float* __restrict__ codes_f,
    const float* __restrict__ ema_cs, const float* __restrict__ ema_w,
    const float* __restrict__ nval, const float* __restrict__ loss_acc,
    float* __restrict__ out_newcs, float* __restrict__ out_neww,
    float* __restrict__ out_newemb, float* __restrict__ out_loss) {
  __shared__ int   list[8192];
  __shared__ int   lcount;
  __shared__ float red[4][64];

  const int tid = threadIdx.x;
  const int k = blockIdx.x;
  const float kf = (float)k;
  const int lane = tid & 63;
  const int g = tid >> 6, d = tid & 63;

  if (tid == 0) lcount = 0;
  __syncthreads();

  float acc = 0.f;
  int total = 0;

  for (int w = 0; w < 8; ++w) {
    // ---- scan 8192 codes: float4 per thread x 8 rounds ----
#pragma unroll 2
    for (int r = 0; r < 8; ++r) {
      const int base = w * 8192 + r * 1024 + tid * 4;
      const float4 cv = *reinterpret_cast<const float4*>(codes_f + base);
      const float c4[4] = {cv.x, cv.y, cv.z, cv.w};
#pragma unroll
      for (int c = 0; c < 4; ++c) {
        const bool match = (c4[c] == kf);
        const unsigned long long mask = __ballot(match);
        if (mask) {
          int wbase;
          if (lane == 0) wbase = atomicAdd(&lcount, __popcll(mask));
          wbase = __shfl(wbase, 0, 64);
          if (match) {
            const int below = __popcll(mask & ((1ull << lane) - 1ull));
            list[wbase + below] = base + c;
          }
        }
      }
    }
    __syncthreads();

    // ---- drain: group g takes list[g], list[g+4], ... ; lane d sums dim d ----
    const int cnt = lcount;
    total += cnt;
    for (int j = g; j < cnt; j += 4) {
      const int tok = list[j];
      acc += z[(size_t)(tok >> 11) * (Dn * Tn) + (size_t)d * Tn + (tok & 2047)];
    }
    __syncthreads();
    if (tid == 0) lcount = 0;
    __syncthreads();
  }

  red[g][d] = acc;
  __syncthreads();

  if (tid < 64) {
    const float dwd = (red[0][tid] + red[1][tid]) + (red[2][tid] + red[3][tid]);
    const float newcs = fmaf(OMD, (float)total, DECAY * ema_cs[k]);
    const float n = nval[0];
    const float cluster = (newcs + EPSV) / (n + (float)Kn * EPSV) * n;
    const float wv = fmaf(OMD, dwd, DECAY * ema_w[(size_t)k * Dn + tid]);
    out_neww[(size_t)k * Dn + tid] = wv;
    out_newemb[(size_t)k * Dn + tid] = wv / cluster;
    if (tid == 0) {
      out_newcs[k] = newcs;
      if (k == 0) out_loss[0] = COMMIT * loss_acc[0] / (float)(Bn * Tn * Dn);
    }
  }
}

extern "C" void kernel_launch(void* const* d_in, const int* in_sizes, int n_in,
                              void* d_out, int out_size, void* d_ws, size_t ws_size,
                              hipStream_t stream) {
  const float* z      = (const float*)d_in[0];
  const float* emb    = (const float*)d_in[1];
  const float* ema_cs = (const float*)d_in[2];
  const float* ema_w  = (const float*)d_in[3];

  float* out = (float*)d_out;
  float* o_quant  = out;                       // 4194304
  float* o_loss   = out + 4194304;             // 1
  float* o_codes  = out + 4194305;             // 65536
  float* o_newemb = out + 4259841;             // 65536
  float* o_newcs  = out + 4325377;             // 1024
  float* o_neww   = out + 4326401;             // 65536

  float* ws       = (float*)d_ws;
  float* loss_acc = ws;                        // 1
  float* nval     = ws + 1;                    // 1
  float* esq      = ws + 2;                    // 1024

  hipMemsetAsync(loss_acc, 0, sizeof(float), stream);

  vq_prep_kernel<<<5, 256, 0, stream>>>(emb, ema_cs, esq, nval);
  vq_main_kernel<<<512, 512, 0, stream>>>(z, emb, esq, o_quant, o_codes, loss_acc);
  vq_dw_kernel<<<1024, 256, 0, stream>>>(z, o_codes, ema_cs, ema_w, nval, loss_acc,
                                         o_newcs, o_neww, o_newemb, o_loss);
}

// Round 17
// 307.931 us; speedup vs baseline: 3.5551x; 1.1561x over previous
//
#include <hip/hip_runtime.h>

// VQ-VAE EMA quantizer. B=32, D=64, T=2048, K=1024, N=B*T=65536.
// R6: vq_dw was HBM-fetch-bound (146MB, 16x over-fetch: z is [b][d][t] so a
// token's row spans 64 cache lines). Main kernel now also emits zt[token][d]
// (coalesced, from the LDS tile it already has); dw gathers contiguously.

constexpr int Bn = 32, Dn = 64, Tn = 2048, Kn = 1024;
constexpr float DECAY = 0.99f, OMD = 0.01f, EPSV = 1e-5f, COMMIT = 0.25f;

// ---------------- kernel 1: esq (blocks 0-3) + sum(ema_cs) -> n (block 4) ----
__global__ __launch_bounds__(256) void vq_prep_kernel(const float* __restrict__ emb,
                                                      const float* __restrict__ ema_cs,
                                                      float* __restrict__ esq,
                                                      float* __restrict__ nval) {
  if (blockIdx.x < 4) {
    int k = blockIdx.x * 256 + threadIdx.x;
    const float4* e4 = reinterpret_cast<const float4*>(emb + (size_t)k * Dn);
    float a0 = 0.f, a1 = 0.f, a2 = 0.f, a3 = 0.f;
#pragma unroll
    for (int q = 0; q < 16; ++q) {
      float4 v = e4[q];
      a0 = fmaf(v.x, v.x, a0);
      a1 = fmaf(v.y, v.y, a1);
      a2 = fmaf(v.z, v.z, a2);
      a3 = fmaf(v.w, v.w, a3);
    }
    esq[k] = (a0 + a1) + (a2 + a3);
  } else {
    __shared__ float wred[4];
    const int tid = threadIdx.x;
    float s = ema_cs[tid] + ema_cs[tid + 256] + ema_cs[tid + 512] + ema_cs[tid + 768];
#pragma unroll
    for (int off = 32; off > 0; off >>= 1) s += __shfl_down(s, off, 64);
    if ((tid & 63) == 0) wred[tid >> 6] = s;
    __syncthreads();
    if (tid == 0)
      nval[0] = fmaf(DECAY, (wred[0] + wred[1]) + (wred[2] + wred[3]),
                     OMD * (float)(Bn * Tn));
  }
}

// ---------------- kernel 2: distances, argmin, codes, quant, loss, zt ----------------
__global__ __launch_bounds__(512, 4) void vq_main_kernel(
    const float* __restrict__ z, const float* __restrict__ emb,
    const float* __restrict__ esq_g, float* __restrict__ out_quant,
    float* __restrict__ out_codes, float* __restrict__ loss_acc,
    float* __restrict__ zt, int use_zt) {
  __shared__ float As[64][132];     // A[k][token], +4 pad
  __shared__ float Bs[64 * 128];    // B[k][code]; reused for argmin merge
  __shared__ float zsq_s[128];
  __shared__ float esq_s[128];
  __shared__ float lred[8];

  const int tid = threadIdx.x;
  const int blk = blockIdx.x;          // 512 blocks
  const int b  = blk >> 4;             // 16 blocks per batch element
  const int t0 = (blk & 15) * 128;
  const float* zb = z + (size_t)b * (Dn * Tn) + t0;

  // ---- stage A (once): thread d=tid>>3 stages 16 floats of row d ----
  {
    const int d = tid >> 3, seg = tid & 7;
    const float4* src = reinterpret_cast<const float4*>(zb + (size_t)d * Tn + 16 * seg);
#pragma unroll
    for (int j = 0; j < 4; ++j)
      *reinterpret_cast<float4*>(&As[d][16 * seg + 4 * j]) = src[j];
  }
  __syncthreads();

  if (tid < 128) {
    float a0 = 0.f, a1 = 0.f, a2 = 0.f, a3 = 0.f;
#pragma unroll
    for (int k = 0; k < 64; k += 4) {
      a0 = fmaf(As[k + 0][tid], As[k + 0][tid], a0);
      a1 = fmaf(As[k + 1][tid], As[k + 1][tid], a1);
      a2 = fmaf(As[k + 2][tid], As[k + 2][tid], a2);
      a3 = fmaf(As[k + 3][tid], As[k + 3][tid], a3);
    }
    zsq_s[tid] = (a0 + a1) + (a2 + a3);
  }

  const int n_t = tid & 15;     // codes {4n_t+j, 64+4n_t+j} per chunk
  const int m_t = tid >> 4;     // tokens 4m_t..4m_t+3

  float mind[4] = {INFINITY, INFINITY, INFINITY, INFINITY};
  int   mini[4] = {0, 0, 0, 0};

  for (int c8 = 0; c8 < 8; ++c8) {
    const int c0 = c8 * 128;
    {
      const int cl = tid >> 2, q = tid & 3;
      const float4* src = reinterpret_cast<const float4*>(emb + (size_t)(c0 + cl) * Dn + 16 * q);
#pragma unroll
      for (int u = 0; u < 4; ++u) {
        float4 v = src[u];
        const int kb = 16 * q + 4 * u;
        Bs[(kb + 0) * 128 + cl] = v.x;
        Bs[(kb + 1) * 128 + cl] = v.y;
        Bs[(kb + 2) * 128 + cl] = v.z;
        Bs[(kb + 3) * 128 + cl] = v.w;
      }
      if (tid < 128) esq_s[tid] = esq_g[c0 + tid];
    }
    __syncthreads();

    float acc[4][8];
#pragma unroll
    for (int m = 0; m < 4; ++m)
#pragma unroll
      for (int j = 0; j < 8; ++j) acc[m][j] = 0.f;

#pragma unroll 8
    for (int k = 0; k < 64; ++k) {
      float4 av = *reinterpret_cast<const float4*>(&As[k][4 * m_t]);
      float4 b0 = *reinterpret_cast<const float4*>(&Bs[k * 128 + 4 * n_t]);
      float4 b1 = *reinterpret_cast<const float4*>(&Bs[k * 128 + 64 + 4 * n_t]);
      const float a[4]  = {av.x, av.y, av.z, av.w};
      const float bb[8] = {b0.x, b0.y, b0.z, b0.w, b1.x, b1.y, b1.z, b1.w};
#pragma unroll
      for (int m = 0; m < 4; ++m)
#pragma unroll
        for (int j = 0; j < 8; ++j)
          acc[m][j] = fmaf(a[m], bb[j], acc[m][j]);
    }

#pragma unroll
    for (int m = 0; m < 4; ++m) {
      const float zq = zsq_s[4 * m_t + m];
#pragma unroll
      for (int j = 0; j < 8; ++j) {
        const int cc = (j < 4) ? (4 * n_t + j) : (64 + 4 * n_t + (j - 4));
        const float dist = fmaf(-2.f, acc[m][j], zq + esq_s[cc]);
        if (dist < mind[m]) { mind[m] = dist; mini[m] = c0 + cc; }
      }
    }
    __syncthreads();
  }

  // ---- cross-thread argmin merge (reuse Bs; stride 17) ----
  float* red_d = Bs;
  int*   red_i = (int*)(Bs + 2176);
  int*   idxs  = (int*)(Bs + 4352);
#pragma unroll
  for (int m = 0; m < 4; ++m) {
    red_d[(4 * m_t + m) * 17 + n_t] = mind[m];
    red_i[(4 * m_t + m) * 17 + n_t] = mini[m];
  }
  __syncthreads();
  if (tid < 128) {
    float md = red_d[tid * 17];
    int mi = red_i[tid * 17];
#pragma unroll
    for (int s = 1; s < 16; ++s) {
      float dv = red_d[tid * 17 + s];
      int iv = red_i[tid * 17 + s];
      if (dv < md || (dv == md && iv < mi)) { md = dv; mi = iv; }
    }
    idxs[tid] = mi;
    out_codes[(size_t)b * Tn + t0 + tid] = (float)mi;
  }
  __syncthreads();

  // ---- epilogue: quant write, direct loss, zt write ----
  const int l = tid & 127, g = tid >> 7;
  const int myidx = idxs[l];
  const float* erow = emb + (size_t)myidx * Dn;
  float* qout = out_quant + (size_t)b * (Dn * Tn) + t0 + l;
  float lpart = 0.f;
#pragma unroll
  for (int j = 0; j < 16; ++j) {
    const int d = 16 * g + j;
    const float e = erow[d];
    const float diff = e - As[d][l];
    qout[(size_t)d * Tn] = e;
    lpart = fmaf(diff, diff, lpart);
  }
  if (use_zt) {
    float* dst = zt + ((size_t)b * Tn + t0 + l) * Dn + 16 * g;
#pragma unroll
    for (int jj = 0; jj < 4; ++jj) {
      const int d = 16 * g + 4 * jj;
      float4 v = make_float4(As[d][l], As[d + 1][l], As[d + 2][l], As[d + 3][l]);
      *reinterpret_cast<float4*>(dst + 4 * jj) = v;
    }
  }
#pragma unroll
  for (int off = 32; off > 0; off >>= 1) lpart += __shfl_down(lpart, off, 64);
  if ((tid & 63) == 0) lred[tid >> 6] = lpart;
  __syncthreads();
  if (tid == 0) {
    float s = 0.f;
#pragma unroll
    for (int w8 = 0; w8 < 8; ++w8) s += lred[w8];
    atomicAdd(loss_acc, s);
  }
}

// ---------------- kernel 3: per-code gather -> counts, dw, all EMA outputs ----
__global__ __launch_bounds__(256) void vq_dw_kernel(
    const float* __restrict__ z, const float* __restrict__ zt,
    const float* __restrict__ codes_f,
    const float* __restrict__ ema_cs, const float* __restrict__ ema_w,
    const float* __restrict__ nval, const float* __restrict__ loss_acc,
    float* __restrict__ out_newcs, float* __restrict__ out_neww,
    float* __restrict__ out_newemb, float* __restrict__ out_loss, int use_zt) {
  __shared__ int   list[8192];
  __shared__ int   lcount;
  __shared__ float red[4][64];

  const int tid = threadIdx.x;
  const int k = blockIdx.x;
  const float kf = (float)k;
  const int lane = tid & 63;
  const int g = tid >> 6, d = tid & 63;

  if (tid == 0) lcount = 0;
  __syncthreads();

  float acc = 0.f;
  int total = 0;

  for (int w = 0; w < 8; ++w) {
    // ---- scan 8192 codes: float4 per thread x 8 rounds ----
#pragma unroll 2
    for (int r = 0; r < 8; ++r) {
      const int base = w * 8192 + r * 1024 + tid * 4;
      const float4 cv = *reinterpret_cast<const float4*>(codes_f + base);
      const float c4[4] = {cv.x, cv.y, cv.z, cv.w};
#pragma unroll
      for (int c = 0; c < 4; ++c) {
        const bool match = (c4[c] == kf);
        const unsigned long long mask = __ballot(match);
        if (mask) {
          int wbase;
          if (lane == 0) wbase = atomicAdd(&lcount, __popcll(mask));
          wbase = __shfl(wbase, 0, 64);
          if (match) {
            const int below = __popcll(mask & ((1ull << lane) - 1ull));
            list[wbase + below] = base + c;
          }
        }
      }
    }
    __syncthreads();

    // ---- drain: group g takes list[g], list[g+4], ...; lane d sums dim d ----
    const int cnt = lcount;
    total += cnt;
    if (use_zt) {
      for (int j = g; j < cnt; j += 4) {
        const int tok = list[j];
        acc += zt[(size_t)tok * Dn + d];          // coalesced: 256B/token
      }
    } else {
      for (int j = g; j < cnt; j += 4) {
        const int tok = list[j];
        acc += z[(size_t)(tok >> 11) * (Dn * Tn) + (size_t)d * Tn + (tok & 2047)];
      }
    }
    __syncthreads();
    if (tid == 0) lcount = 0;
    __syncthreads();
  }

  red[g][d] = acc;
  __syncthreads();

  if (tid < 64) {
    const float dwd = (red[0][tid] + red[1][tid]) + (red[2][tid] + red[3][tid]);
    const float newcs = fmaf(OMD, (float)total, DECAY * ema_cs[k]);
    const float n = nval[0];
    const float cluster = (newcs + EPSV) / (n + (float)Kn * EPSV) * n;
    const float wv = fmaf(OMD, dwd, DECAY * ema_w[(size_t)k * Dn + tid]);
    out_neww[(size_t)k * Dn + tid] = wv;
    out_newemb[(size_t)k * Dn + tid] = wv / cluster;
    if (tid == 0) {
      out_newcs[k] = newcs;
      if (k == 0) out_loss[0] = COMMIT * loss_acc[0] / (float)(Bn * Tn * Dn);
    }
  }
}

extern "C" void kernel_launch(void* const* d_in, const int* in_sizes, int n_in,
                              void* d_out, int out_size, void* d_ws, size_t ws_size,
                              hipStream_t stream) {
  const float* z      = (const float*)d_in[0];
  const float* emb    = (const float*)d_in[1];
  const float* ema_cs = (const float*)d_in[2];
  const float* ema_w  = (const float*)d_in[3];

  float* out = (float*)d_out;
  float* o_quant  = out;                       // 4194304
  float* o_loss   = out + 4194304;             // 1
  float* o_codes  = out + 4194305;             // 65536
  float* o_newemb = out + 4259841;             // 65536
  float* o_newcs  = out + 4325377;             // 1024
  float* o_neww   = out + 4326401;             // 65536

  float* ws       = (float*)d_ws;
  float* loss_acc = ws;                        // 1
  float* nval     = ws + 1;                    // 1
  float* esq      = ws + 2;                    // 1024
  float* zt       = ws + 2048;                 // 4194304 (16.8 MB), if it fits

  const int use_zt = (ws_size >= (size_t)(2048 + 4194304) * sizeof(float)) ? 1 : 0;

  hipMemsetAsync(loss_acc, 0, sizeof(float), stream);

  vq_prep_kernel<<<5, 256, 0, stream>>>(emb, ema_cs, esq, nval);
  vq_main_kernel<<<512, 512, 0, stream>>>(z, emb, esq, o_quant, o_codes, loss_acc,
                                          zt, use_zt);
  vq_dw_kernel<<<1024, 256, 0, stream>>>(z, zt, o_codes, ema_cs, ema_w, nval,
                                         loss_acc, o_newcs, o_neww, o_newemb,
                                         o_loss, use_zt);
}